// Round 10
// baseline (22.950 us; speedup 1.0000x reference)
//
#include <hip/hip_runtime.h>
#include <hip/hip_bf16.h>
#include <math.h>

#define BB 2048
#define CC 1000
#define DD 64
#define CPB 16             // classes per stats block
#define NCB 63             // stats blocks (63*16 = 1008 >= 1000)
constexpr float EPS_STATS = 1e-5f;
constexpr float EPS_PREC  = 1e-6f;
constexpr float TSUM = (float)BB + (float)CC * EPS_STATS;  // counts.sum()

typedef __attribute__((ext_vector_type(8))) short bf8;     // 8 bf16 (4 VGPR)
typedef __attribute__((ext_vector_type(4))) float f32x4;   // MFMA acc

__device__ inline unsigned short f2bf(float f) {           // RNE f32->bf16
    __hip_bfloat16 h = __float2bfloat16(f);
    return *reinterpret_cast<unsigned short*>(&h);
}

// --- K_A: stats. 63 blocks x 16 classes. Disjoint coverage: each sample row
// is gathered by exactly one block, so the gather also accumulates local
// sum(z^2); block emits part[bid][d] = t2_local - sum_c corr_c. Summed over
// blocks this is pooled*TSUM (before /TSUM + eps).
__global__ void __launch_bounds__(256)
k_stats(const float* __restrict__ z, const int* __restrict__ y,
        float* __restrict__ mean, float* __restrict__ logpr,
        float* __restrict__ part) {
    __shared__ __align__(16) int ys[BB];        // 8 KB
    __shared__ int mlist[BB];                   // 8 KB (pathological-y safe)
    __shared__ float sacc[CPB * DD];            // 4 KB per-class sums
    __shared__ float corrv[CPB * DD];           // 4 KB
    __shared__ float t2s[DD];                   // 256 B
    __shared__ int cnts[CPB];
    __shared__ int mcnt;
    int tid = threadIdx.x, bid = blockIdx.x;

    const int4* y4 = reinterpret_cast<const int4*>(y);
    int4* ys4 = reinterpret_cast<int4*>(ys);
    ys4[tid] = y4[tid];
    ys4[tid + 256] = y4[tid + 256];
    #pragma unroll
    for (int i = 0; i < CPB * DD / 256; ++i) sacc[tid + i * 256] = 0.f;
    if (tid < DD) t2s[tid] = 0.f;
    if (tid < CPB) cnts[tid] = 0;
    if (tid == 0) mcnt = 0;
    __syncthreads();

    // scan: compact matches (b, class-local cl) into mlist
    int cbase = bid * CPB;
    #pragma unroll
    for (int i = 0; i < BB / 256; ++i) {
        int b = tid + i * 256;
        int cl = ys[b] - cbase;
        if ((unsigned)cl < (unsigned)CPB) {
            atomicAdd(&cnts[cl], 1);
            int p = atomicAdd(&mcnt, 1);        // ~32 LDS atomics per block
            mlist[p] = b * CPB + cl;
        }
    }
    __syncthreads();

    // gather: 16 entries/round; lane-group (lane>>4) picks entry slot,
    // (lane&15)*4 picks dims -> one float4 per lane; t2 accumulated locally.
    int n = mcnt;
    int w = tid >> 6, lane = tid & 63;
    int eg = w * 4 + (lane >> 4);               // entry slot 0..15
    int d4 = (lane & 15) * 4;
    float t2x = 0.f, t2y = 0.f, t2z = 0.f, t2w = 0.f;
    for (int j0 = 0; j0 < n; j0 += 16) {
        int j = j0 + eg;
        if (j < n) {
            int e = mlist[j];
            float4 v = *reinterpret_cast<const float4*>(
                &z[(size_t)(e / CPB) * DD + d4]);
            float* sa = &sacc[(e % CPB) * DD + d4];
            atomicAdd(sa + 0, v.x);
            atomicAdd(sa + 1, v.y);
            atomicAdd(sa + 2, v.z);
            atomicAdd(sa + 3, v.w);
            t2x = fmaf(v.x, v.x, t2x);
            t2y = fmaf(v.y, v.y, t2y);
            t2z = fmaf(v.z, v.z, t2z);
            t2w = fmaf(v.w, v.w, t2w);
        }
    }
    atomicAdd(&t2s[d4 + 0], t2x);               // 16-way LDS contention, tiny
    atomicAdd(&t2s[d4 + 1], t2y);
    atomicAdd(&t2s[d4 + 2], t2z);
    atomicAdd(&t2s[d4 + 3], t2w);
    __syncthreads();

    // finalize: 16*64 = 1024 (cl,d) slots over 4 iterations
    #pragma unroll
    for (int i = 0; i < CPB * DD / 256; ++i) {
        int idx = tid + i * 256;
        int cl = idx >> 6, d = idx & 63;
        float s  = sacc[idx];
        float nn = (float)cnts[cl];
        float ce = nn + EPS_STATS;
        float inv = 1.0f / ce;
        int c = cbase + cl;
        if (c < CC) {
            mean[(size_t)c * DD + d] = s * inv;
            if (d == 0) logpr[c] = logf(ce / TSUM);
        }
        // class corr at dim d: s^2 (n+2e)/(n+e)^2  (== 2ms - n m^2 exactly)
        corrv[idx] = s * s * (nn + 2.f * EPS_STATS) * inv * inv;
    }
    __syncthreads();
    if (tid < DD) {
        float a = t2s[tid];
        #pragma unroll
        for (int cl = 0; cl < CPB; ++cl) a -= corrv[cl * DD + tid];
        part[bid * DD + tid] = a;
    }
}

// --- K_B: fused precision + MFMA scoring. Grid (32,16); block = 64b x 64c tile.
// out[b][c] = (logpr[c] - 0.5*K_c) + dot(w_c, z_b) - 0.5*S_b,  w = p*mean.
__global__ void __launch_bounds__(256)
k_score_mfma(const float* __restrict__ z, const float* __restrict__ mean,
             const float* __restrict__ logpr, const float* __restrict__ part,
             float* __restrict__ out) {
    __shared__ __align__(16) float red[16][DD];
    __shared__ float ps_s[DD];
    int tid = threadIdx.x;

    // precision: reduce 63 partial rows, float4-vectorized.
    {
        int r0 = tid >> 4;            // 0..15
        int c4 = (tid & 15) * 4;      // 0,4,..,60
        float ax = 0.f, ay = 0.f, az = 0.f, aw = 0.f;
        for (int p = r0; p < NCB; p += 16) {
            float4 v = *reinterpret_cast<const float4*>(&part[p * DD + c4]);
            ax += v.x; ay += v.y; az += v.z; aw += v.w;
        }
        float4 a4 = {ax, ay, az, aw};
        *reinterpret_cast<float4*>(&red[r0][c4]) = a4;
    }
    __syncthreads();
    if (tid < DD) {
        float acc = 0.f;
        #pragma unroll
        for (int g = 0; g < 16; ++g) acc += red[g][tid];
        float pooled = acc / TSUM + EPS_STATS;
        ps_s[tid] = 1.0f / fmaxf(pooled, EPS_PREC);
    }
    __syncthreads();

    int wv = tid >> 6, l = tid & 63;
    int lr = l & 15, lg = l >> 4;          // lane-row (M/N idx), k-group
    int b0 = blockIdx.x * 64 + wv * 16;    // wave's 16 output rows
    int c0 = blockIdx.y * 64;              // block's 64 classes

    float ps0[8], ps1[8];
    #pragma unroll
    for (int j = 0; j < 8; ++j) { ps0[j] = ps_s[lg * 8 + j]; ps1[j] = ps_s[32 + lg * 8 + j]; }

    // A fragments: z row (b0+lr) via float4; also S_b partial
    const float* zrow = z + (size_t)(b0 + lr) * DD;
    float4 z00 = *reinterpret_cast<const float4*>(zrow + lg * 8);
    float4 z01 = *reinterpret_cast<const float4*>(zrow + lg * 8 + 4);
    float4 z10 = *reinterpret_cast<const float4*>(zrow + 32 + lg * 8);
    float4 z11 = *reinterpret_cast<const float4*>(zrow + 32 + lg * 8 + 4);
    float zf0[8] = {z00.x, z00.y, z00.z, z00.w, z01.x, z01.y, z01.z, z01.w};
    float zf1[8] = {z10.x, z10.y, z10.z, z10.w, z11.x, z11.y, z11.z, z11.w};
    bf8 a0, a1;
    float sbp = 0.f;
    #pragma unroll
    for (int j = 0; j < 8; ++j) {
        a0[j] = (short)f2bf(zf0[j]);
        a1[j] = (short)f2bf(zf1[j]);
        sbp = fmaf(ps0[j] * zf0[j], zf0[j], sbp);
        sbp = fmaf(ps1[j] * zf1[j], zf1[j], sbp);
    }
    sbp += __shfl_xor(sbp, 16);
    sbp += __shfl_xor(sbp, 32);            // lane holds S for row b0+lr

    f32x4 acc[4];
    float cstv[4];
    #pragma unroll
    for (int ct = 0; ct < 4; ++ct) {
        int c = c0 + ct * 16 + lr;
        int cm = (c < CC) ? c : (CC - 1);
        const float* mrow = mean + (size_t)cm * DD;
        float4 m00 = *reinterpret_cast<const float4*>(mrow + lg * 8);
        float4 m01 = *reinterpret_cast<const float4*>(mrow + lg * 8 + 4);
        float4 m10 = *reinterpret_cast<const float4*>(mrow + 32 + lg * 8);
        float4 m11 = *reinterpret_cast<const float4*>(mrow + 32 + lg * 8 + 4);
        float mf0[8] = {m00.x, m00.y, m00.z, m00.w, m01.x, m01.y, m01.z, m01.w};
        float mf1[8] = {m10.x, m10.y, m10.z, m10.w, m11.x, m11.y, m11.z, m11.w};
        bf8 w0, w1;
        float kc = 0.f;
        #pragma unroll
        for (int j = 0; j < 8; ++j) {
            float wf0 = ps0[j] * mf0[j], wf1 = ps1[j] * mf1[j];
            w0[j] = (short)f2bf(wf0);
            w1[j] = (short)f2bf(wf1);
            kc = fmaf(wf0, mf0[j], kc);
            kc = fmaf(wf1, mf1[j], kc);
        }
        kc += __shfl_xor(kc, 16);
        kc += __shfl_xor(kc, 32);          // K_c for class cm
        cstv[ct] = fmaf(-0.5f, kc, logpr[cm]);
        f32x4 a = {0.f, 0.f, 0.f, 0.f};
        a = __builtin_amdgcn_mfma_f32_16x16x32_bf16(a0, w0, a, 0, 0, 0);
        a = __builtin_amdgcn_mfma_f32_16x16x32_bf16(a1, w1, a, 0, 0, 0);
        acc[ct] = a;
    }

    // epilogue: D row = lg*4+r, col = lr
    float sbv[4];
    #pragma unroll
    for (int r = 0; r < 4; ++r) sbv[r] = __shfl(sbp, lg * 4 + r);
    #pragma unroll
    for (int ct = 0; ct < 4; ++ct) {
        int c = c0 + ct * 16 + lr;
        if (c < CC) {
            #pragma unroll
            for (int r = 0; r < 4; ++r) {
                int b = b0 + lg * 4 + r;
                out[(size_t)b * CC + c] = acc[ct][r] + cstv[ct] - 0.5f * sbv[r];
            }
        }
    }
}

extern "C" void kernel_launch(void* const* d_in, const int* in_sizes, int n_in,
                              void* d_out, int out_size, void* d_ws, size_t ws_size,
                              hipStream_t stream) {
    const float* z = (const float*)d_in[0];
    const int*   y = (const int*)d_in[1];
    float* out = (float*)d_out;

    // ws: all arrays written every call before read; no zeroing needed.
    float* mean  = (float*)d_ws;            // 64000 (class-major [c][d])
    float* logpr = mean + DD * CC;          // 1000
    float* part  = logpr + CC;              // 63*64 = 4032

    k_stats<<<NCB, 256, 0, stream>>>(z, y, mean, logpr, part);
    dim3 grid(BB / 64, (CC + 63) / 64);     // 32 x 16
    k_score_mfma<<<grid, 256, 0, stream>>>(z, mean, logpr, part, out);
}

// Round 11
// 22.291 us; speedup vs baseline: 1.0296x; 1.0296x over previous
//
#include <hip/hip_runtime.h>
#include <hip/hip_bf16.h>
#include <math.h>

#define BB 2048
#define CC 1000
#define DD 64
#define CPB 8              // classes per stats block
#define NCB 125            // stats blocks (125*8 = 1000 exactly)
constexpr float EPS_STATS = 1e-5f;
constexpr float EPS_PREC  = 1e-6f;
constexpr float TSUM = (float)BB + (float)CC * EPS_STATS;  // counts.sum()

typedef __attribute__((ext_vector_type(8))) short bf8;     // 8 bf16 (4 VGPR)
typedef __attribute__((ext_vector_type(4))) float f32x4;   // MFMA acc

__device__ inline unsigned short f2bf(float f) {           // RNE f32->bf16
    __hip_bfloat16 h = __float2bfloat16(f);
    return *reinterpret_cast<unsigned short*>(&h);
}

// --- K_A: stats. 125 blocks x 8 classes (R9 geometry, proven 21.06us) plus
// disjoint-coverage T2 fold-in: each sample row is gathered by exactly one
// block, so the gather also accumulates local sum(z^2) and the block emits
// part[bid][d] = t2_local - sum_cl corr_cl. Sum over blocks = pooled*TSUM.
__global__ void __launch_bounds__(256)
k_stats(const float* __restrict__ z, const int* __restrict__ y,
        float* __restrict__ mean, float* __restrict__ logpr,
        float* __restrict__ part) {
    __shared__ __align__(16) int ys[BB];        // 8 KB
    __shared__ int mlist[BB];                   // 8 KB (pathological-y safe)
    __shared__ float sacc[CPB * DD];            // 2 KB per-class sums
    __shared__ float corrv[CPB * DD];           // 2 KB
    __shared__ float t2s[DD];                   // 256 B
    __shared__ int cnts[CPB];
    __shared__ int mcnt;
    int tid = threadIdx.x, bid = blockIdx.x;

    const int4* y4 = reinterpret_cast<const int4*>(y);
    int4* ys4 = reinterpret_cast<int4*>(ys);
    ys4[tid] = y4[tid];
    ys4[tid + 256] = y4[tid + 256];
    sacc[tid] = 0.f; sacc[tid + 256] = 0.f;     // 512 == CPB*DD exactly
    if (tid < DD) t2s[tid] = 0.f;
    if (tid < CPB) cnts[tid] = 0;
    if (tid == 0) mcnt = 0;
    __syncthreads();

    // scan: compact matches (b, class-local cl) into mlist
    int cbase = bid * CPB;
    #pragma unroll
    for (int i = 0; i < BB / 256; ++i) {
        int b = tid + i * 256;
        int cl = ys[b] - cbase;
        if ((unsigned)cl < (unsigned)CPB) {
            atomicAdd(&cnts[cl], 1);
            int p = atomicAdd(&mcnt, 1);        // ~16 LDS atomics per block
            mlist[p] = b * CPB + cl;
        }
    }
    __syncthreads();

    // gather: 16 entries/round; lane-group (lane>>4) picks entry slot,
    // (lane&15)*4 picks dims -> one float4 per lane; t2 accumulated locally.
    int n = mcnt;
    int w = tid >> 6, lane = tid & 63;
    int eg = w * 4 + (lane >> 4);               // entry slot 0..15
    int d4 = (lane & 15) * 4;
    float t2x = 0.f, t2y = 0.f, t2z = 0.f, t2w = 0.f;
    for (int j0 = 0; j0 < n; j0 += 16) {
        int j = j0 + eg;
        if (j < n) {
            int e = mlist[j];
            float4 v = *reinterpret_cast<const float4*>(
                &z[(size_t)(e >> 3) * DD + d4]);
            float* sa = &sacc[(e & 7) * DD + d4];
            atomicAdd(sa + 0, v.x);
            atomicAdd(sa + 1, v.y);
            atomicAdd(sa + 2, v.z);
            atomicAdd(sa + 3, v.w);
            t2x = fmaf(v.x, v.x, t2x);
            t2y = fmaf(v.y, v.y, t2y);
            t2z = fmaf(v.z, v.z, t2z);
            t2w = fmaf(v.w, v.w, t2w);
        }
    }
    atomicAdd(&t2s[d4 + 0], t2x);               // 16-way LDS contention, tiny
    atomicAdd(&t2s[d4 + 1], t2y);
    atomicAdd(&t2s[d4 + 2], t2z);
    atomicAdd(&t2s[d4 + 3], t2w);
    __syncthreads();

    // finalize: 8*64 = 512 (cl,d) slots over 2 iterations
    #pragma unroll
    for (int i = 0; i < 2; ++i) {
        int idx = tid + i * 256;
        int cl = idx >> 6, d = idx & 63;
        float s  = sacc[idx];
        float nn = (float)cnts[cl];
        float ce = nn + EPS_STATS;
        float inv = 1.0f / ce;
        int c = cbase + cl;                     // < 1000 always (125*8=1000)
        mean[(size_t)c * DD + d] = s * inv;
        if (d == 0) logpr[c] = logf(ce / TSUM);
        // class corr at dim d: s^2 (n+2e)/(n+e)^2  (== 2ms - n m^2 exactly)
        corrv[idx] = s * s * (nn + 2.f * EPS_STATS) * inv * inv;
    }
    __syncthreads();
    if (tid < DD) {
        float a = t2s[tid];
        #pragma unroll
        for (int cl = 0; cl < CPB; ++cl) a -= corrv[cl * DD + tid];
        part[bid * DD + tid] = a;
    }
}

// --- K_B: fused precision + MFMA scoring. Grid (32,16); block = 64b x 64c tile.
// out[b][c] = (logpr[c] - 0.5*K_c) + dot(w_c, z_b) - 0.5*S_b,  w = p*mean.
__global__ void __launch_bounds__(256)
k_score_mfma(const float* __restrict__ z, const float* __restrict__ mean,
             const float* __restrict__ logpr, const float* __restrict__ part,
             float* __restrict__ out) {
    __shared__ __align__(16) float red[16][DD];
    __shared__ float ps_s[DD];
    int tid = threadIdx.x;

    // precision: reduce 125 partial rows, float4-vectorized.
    {
        int r0 = tid >> 4;            // 0..15
        int c4 = (tid & 15) * 4;      // 0,4,..,60
        float ax = 0.f, ay = 0.f, az = 0.f, aw = 0.f;
        for (int p = r0; p < NCB; p += 16) {
            float4 v = *reinterpret_cast<const float4*>(&part[p * DD + c4]);
            ax += v.x; ay += v.y; az += v.z; aw += v.w;
        }
        float4 a4 = {ax, ay, az, aw};
        *reinterpret_cast<float4*>(&red[r0][c4]) = a4;
    }
    __syncthreads();
    if (tid < DD) {
        float acc = 0.f;
        #pragma unroll
        for (int g = 0; g < 16; ++g) acc += red[g][tid];
        float pooled = acc / TSUM + EPS_STATS;
        ps_s[tid] = 1.0f / fmaxf(pooled, EPS_PREC);
    }
    __syncthreads();

    int wv = tid >> 6, l = tid & 63;
    int lr = l & 15, lg = l >> 4;          // lane-row (M/N idx), k-group
    int b0 = blockIdx.x * 64 + wv * 16;    // wave's 16 output rows
    int c0 = blockIdx.y * 64;              // block's 64 classes

    float ps0[8], ps1[8];
    #pragma unroll
    for (int j = 0; j < 8; ++j) { ps0[j] = ps_s[lg * 8 + j]; ps1[j] = ps_s[32 + lg * 8 + j]; }

    // A fragments: z row (b0+lr) via float4; also S_b partial
    const float* zrow = z + (size_t)(b0 + lr) * DD;
    float4 z00 = *reinterpret_cast<const float4*>(zrow + lg * 8);
    float4 z01 = *reinterpret_cast<const float4*>(zrow + lg * 8 + 4);
    float4 z10 = *reinterpret_cast<const float4*>(zrow + 32 + lg * 8);
    float4 z11 = *reinterpret_cast<const float4*>(zrow + 32 + lg * 8 + 4);
    float zf0[8] = {z00.x, z00.y, z00.z, z00.w, z01.x, z01.y, z01.z, z01.w};
    float zf1[8] = {z10.x, z10.y, z10.z, z10.w, z11.x, z11.y, z11.z, z11.w};
    bf8 a0, a1;
    float sbp = 0.f;
    #pragma unroll
    for (int j = 0; j < 8; ++j) {
        a0[j] = (short)f2bf(zf0[j]);
        a1[j] = (short)f2bf(zf1[j]);
        sbp = fmaf(ps0[j] * zf0[j], zf0[j], sbp);
        sbp = fmaf(ps1[j] * zf1[j], zf1[j], sbp);
    }
    sbp += __shfl_xor(sbp, 16);
    sbp += __shfl_xor(sbp, 32);            // lane holds S for row b0+lr

    f32x4 acc[4];
    float cstv[4];
    #pragma unroll
    for (int ct = 0; ct < 4; ++ct) {
        int c = c0 + ct * 16 + lr;
        int cm = (c < CC) ? c : (CC - 1);
        const float* mrow = mean + (size_t)cm * DD;
        float4 m00 = *reinterpret_cast<const float4*>(mrow + lg * 8);
        float4 m01 = *reinterpret_cast<const float4*>(mrow + lg * 8 + 4);
        float4 m10 = *reinterpret_cast<const float4*>(mrow + 32 + lg * 8);
        float4 m11 = *reinterpret_cast<const float4*>(mrow + 32 + lg * 8 + 4);
        float mf0[8] = {m00.x, m00.y, m00.z, m00.w, m01.x, m01.y, m01.z, m01.w};
        float mf1[8] = {m10.x, m10.y, m10.z, m10.w, m11.x, m11.y, m11.z, m11.w};
        bf8 w0, w1;
        float kc = 0.f;
        #pragma unroll
        for (int j = 0; j < 8; ++j) {
            float wf0 = ps0[j] * mf0[j], wf1 = ps1[j] * mf1[j];
            w0[j] = (short)f2bf(wf0);
            w1[j] = (short)f2bf(wf1);
            kc = fmaf(wf0, mf0[j], kc);
            kc = fmaf(wf1, mf1[j], kc);
        }
        kc += __shfl_xor(kc, 16);
        kc += __shfl_xor(kc, 32);          // K_c for class cm
        cstv[ct] = fmaf(-0.5f, kc, logpr[cm]);
        f32x4 a = {0.f, 0.f, 0.f, 0.f};
        a = __builtin_amdgcn_mfma_f32_16x16x32_bf16(a0, w0, a, 0, 0, 0);
        a = __builtin_amdgcn_mfma_f32_16x16x32_bf16(a1, w1, a, 0, 0, 0);
        acc[ct] = a;
    }

    // epilogue: D row = lg*4+r, col = lr
    float sbv[4];
    #pragma unroll
    for (int r = 0; r < 4; ++r) sbv[r] = __shfl(sbp, lg * 4 + r);
    #pragma unroll
    for (int ct = 0; ct < 4; ++ct) {
        int c = c0 + ct * 16 + lr;
        if (c < CC) {
            #pragma unroll
            for (int r = 0; r < 4; ++r) {
                int b = b0 + lg * 4 + r;
                out[(size_t)b * CC + c] = acc[ct][r] + cstv[ct] - 0.5f * sbv[r];
            }
        }
    }
}

extern "C" void kernel_launch(void* const* d_in, const int* in_sizes, int n_in,
                              void* d_out, int out_size, void* d_ws, size_t ws_size,
                              hipStream_t stream) {
    const float* z = (const float*)d_in[0];
    const int*   y = (const int*)d_in[1];
    float* out = (float*)d_out;

    // ws: all arrays written every call before read; no zeroing needed.
    float* mean  = (float*)d_ws;            // 64000 (class-major [c][d])
    float* logpr = mean + DD * CC;          // 1000
    float* part  = logpr + CC;              // 125*64 = 8000

    k_stats<<<NCB, 256, 0, stream>>>(z, y, mean, logpr, part);
    dim3 grid(BB / 64, (CC + 63) / 64);     // 32 x 16
    k_score_mfma<<<grid, 256, 0, stream>>>(z, mean, logpr, part, out);
}

// Round 12
// 21.040 us; speedup vs baseline: 1.0908x; 1.0595x over previous
//
#include <hip/hip_runtime.h>
#include <hip/hip_bf16.h>
#include <math.h>

#define BB 2048
#define CC 1000
#define DD 64
#define NCB 125            // class blocks, 8 classes each
#define NTB 16             // T2 blocks, 128 rows each
constexpr float EPS_STATS = 1e-5f;
constexpr float EPS_PREC  = 1e-6f;
constexpr float TSUM = (float)BB + (float)CC * EPS_STATS;  // counts.sum()

typedef __attribute__((ext_vector_type(8))) short bf8;     // 8 bf16 (4 VGPR)
typedef __attribute__((ext_vector_type(4))) float f32x4;   // MFMA acc

__device__ inline unsigned short f2bf(float f) {           // RNE f32->bf16
    __hip_bfloat16 h = __float2bfloat16(f);
    return *reinterpret_cast<unsigned short*>(&h);
}

// --- K_A: stats (R9 configuration — measured best, 21.06us).
// Blocks 0..124: 8 classes each -> mean, logpr, corrPart[bid].
//   scan y (LDS) -> compact match list -> float4 wave gather (16 entries/round,
//   LDS float atomics) -> finalize.
// Blocks 125..140: T2part[tb][d] = partial sum of z^2 over 128 rows.
// (R10/R11 lesson: keep T2 on separate blocks — they fill idle CUs; folding
// t2 into the gather or halving block count puts it on the critical path.)
__global__ void __launch_bounds__(256)
k_stats(const float* __restrict__ z, const int* __restrict__ y,
        float* __restrict__ mean, float* __restrict__ logpr,
        float* __restrict__ corrPart, float* __restrict__ T2part) {
    int tid = threadIdx.x, bid = blockIdx.x;
    if (bid < NCB) {
        __shared__ __align__(16) int ys[BB];    // 8 KB
        __shared__ int mlist[BB];               // 8 KB (pathological-y safe)
        __shared__ float sacc[8 * DD];          // 2 KB per-class sums
        __shared__ float corrv[8 * DD];         // 2 KB
        __shared__ int cnts[8];
        __shared__ int mcnt;

        const int4* y4 = reinterpret_cast<const int4*>(y);
        int4* ys4 = reinterpret_cast<int4*>(ys);
        ys4[tid] = y4[tid];
        ys4[tid + 256] = y4[tid + 256];
        sacc[tid] = 0.f; sacc[tid + 256] = 0.f;
        if (tid < 8) cnts[tid] = 0;
        if (tid == 0) mcnt = 0;
        __syncthreads();

        // scan: compact matches (b, class-local cl) into mlist
        int cbase = bid * 8;
        #pragma unroll
        for (int i = 0; i < BB / 256; ++i) {
            int b = tid + i * 256;
            int cl = ys[b] - cbase;
            if ((unsigned)cl < 8u) {
                atomicAdd(&cnts[cl], 1);
                int p = atomicAdd(&mcnt, 1);    // ~16 LDS atomics per block
                mlist[p] = b * 8 + cl;
            }
        }
        __syncthreads();

        // gather: 16 entries/round; lane-group (lane>>4) picks entry slot,
        // (lane&15)*4 picks dims -> one float4 per lane, 256B row per group.
        int n = mcnt;
        int w = tid >> 6, lane = tid & 63;
        int eg = w * 4 + (lane >> 4);           // entry slot 0..15
        int d4 = (lane & 15) * 4;
        for (int j0 = 0; j0 < n; j0 += 16) {
            int j = j0 + eg;
            if (j < n) {
                int e = mlist[j];
                float4 v = *reinterpret_cast<const float4*>(
                    &z[(size_t)(e >> 3) * DD + d4]);
                float* sa = &sacc[(e & 7) * DD + d4];
                atomicAdd(sa + 0, v.x);
                atomicAdd(sa + 1, v.y);
                atomicAdd(sa + 2, v.z);
                atomicAdd(sa + 3, v.w);
            }
        }
        __syncthreads();

        // finalize: 512 (cl,d) slots over 2 iterations
        #pragma unroll
        for (int i = 0; i < 2; ++i) {
            int idx = tid + i * 256;
            int cl = idx >> 6, d = idx & 63;
            float s  = sacc[idx];
            float nn = (float)cnts[cl];
            float ce = nn + EPS_STATS;
            float inv = 1.0f / ce;
            int c = cbase + cl;
            mean[(size_t)c * DD + d] = s * inv;      // contiguous 2KB per block
            if (d == 0) logpr[c] = logf(ce / TSUM);
            // class corr at dim d: s^2 (n+2e)/(n+e)^2  (== 2ms - n m^2 exactly)
            corrv[idx] = s * s * (nn + 2.f * EPS_STATS) * inv * inv;
        }
        __syncthreads();
        if (tid < DD) {
            float a = 0.f;
            #pragma unroll
            for (int cl = 0; cl < 8; ++cl) a += corrv[cl * DD + tid];
            corrPart[bid * DD + tid] = a;
        }
    } else {
        __shared__ float p2[4][DD];
        int tb = bid - NCB;                     // 0..15
        int d = tid & 63, grp = tid >> 6;
        int r0 = tb * 128 + grp * 32;
        float a = 0.f;
        #pragma unroll 8
        for (int r = 0; r < 32; ++r) {
            float v = z[(size_t)(r0 + r) * DD + d];  // coalesced row reads
            a = fmaf(v, v, a);
        }
        p2[grp][d] = a;
        __syncthreads();
        if (tid < DD)
            T2part[tb * DD + tid] =
                p2[0][tid] + p2[1][tid] + p2[2][tid] + p2[3][tid];
    }
}

// --- K_B: fused precision + MFMA scoring. Grid (32,16); block = 64b x 64c tile.
// out[b][c] = (logpr[c] - 0.5*K_c) + dot(w_c, z_b) - 0.5*S_b,  w = p*mean.
__global__ void __launch_bounds__(256)
k_score_mfma(const float* __restrict__ z, const float* __restrict__ mean,
             const float* __restrict__ logpr, const float* __restrict__ corrPart,
             const float* __restrict__ T2part, float* __restrict__ out) {
    __shared__ __align__(16) float red[16][DD];
    __shared__ float ps_s[DD];
    int tid = threadIdx.x;

    // precision: reduce 141 partial rows (16 T2 + 125 corr), float4-vectorized.
    {
        int r0 = tid >> 4;            // 0..15
        int c4 = (tid & 15) * 4;      // 0,4,..,60
        float4 t = *reinterpret_cast<const float4*>(&T2part[r0 * DD + c4]);
        float ax = t.x, ay = t.y, az = t.z, aw = t.w;
        for (int p = r0; p < NCB; p += 16) {
            float4 v = *reinterpret_cast<const float4*>(&corrPart[p * DD + c4]);
            ax -= v.x; ay -= v.y; az -= v.z; aw -= v.w;
        }
        float4 a4 = {ax, ay, az, aw};
        *reinterpret_cast<float4*>(&red[r0][c4]) = a4;
    }
    __syncthreads();
    if (tid < DD) {
        float acc = 0.f;
        #pragma unroll
        for (int g = 0; g < 16; ++g) acc += red[g][tid];
        float pooled = acc / TSUM + EPS_STATS;
        ps_s[tid] = 1.0f / fmaxf(pooled, EPS_PREC);
    }
    __syncthreads();

    int wv = tid >> 6, l = tid & 63;
    int lr = l & 15, lg = l >> 4;          // lane-row (M/N idx), k-group
    int b0 = blockIdx.x * 64 + wv * 16;    // wave's 16 output rows
    int c0 = blockIdx.y * 64;              // block's 64 classes

    float ps0[8], ps1[8];
    #pragma unroll
    for (int j = 0; j < 8; ++j) { ps0[j] = ps_s[lg * 8 + j]; ps1[j] = ps_s[32 + lg * 8 + j]; }

    // A fragments: z row (b0+lr) via float4; also S_b partial
    const float* zrow = z + (size_t)(b0 + lr) * DD;
    float4 z00 = *reinterpret_cast<const float4*>(zrow + lg * 8);
    float4 z01 = *reinterpret_cast<const float4*>(zrow + lg * 8 + 4);
    float4 z10 = *reinterpret_cast<const float4*>(zrow + 32 + lg * 8);
    float4 z11 = *reinterpret_cast<const float4*>(zrow + 32 + lg * 8 + 4);
    float zf0[8] = {z00.x, z00.y, z00.z, z00.w, z01.x, z01.y, z01.z, z01.w};
    float zf1[8] = {z10.x, z10.y, z10.z, z10.w, z11.x, z11.y, z11.z, z11.w};
    bf8 a0, a1;
    float sbp = 0.f;
    #pragma unroll
    for (int j = 0; j < 8; ++j) {
        a0[j] = (short)f2bf(zf0[j]);
        a1[j] = (short)f2bf(zf1[j]);
        sbp = fmaf(ps0[j] * zf0[j], zf0[j], sbp);
        sbp = fmaf(ps1[j] * zf1[j], zf1[j], sbp);
    }
    sbp += __shfl_xor(sbp, 16);
    sbp += __shfl_xor(sbp, 32);            // lane holds S for row b0+lr

    f32x4 acc[4];
    float cstv[4];
    #pragma unroll
    for (int ct = 0; ct < 4; ++ct) {
        int c = c0 + ct * 16 + lr;
        int cm = (c < CC) ? c : (CC - 1);
        const float* mrow = mean + (size_t)cm * DD;
        float4 m00 = *reinterpret_cast<const float4*>(mrow + lg * 8);
        float4 m01 = *reinterpret_cast<const float4*>(mrow + lg * 8 + 4);
        float4 m10 = *reinterpret_cast<const float4*>(mrow + 32 + lg * 8);
        float4 m11 = *reinterpret_cast<const float4*>(mrow + 32 + lg * 8 + 4);
        float mf0[8] = {m00.x, m00.y, m00.z, m00.w, m01.x, m01.y, m01.z, m01.w};
        float mf1[8] = {m10.x, m10.y, m10.z, m10.w, m11.x, m11.y, m11.z, m11.w};
        bf8 w0, w1;
        float kc = 0.f;
        #pragma unroll
        for (int j = 0; j < 8; ++j) {
            float wf0 = ps0[j] * mf0[j], wf1 = ps1[j] * mf1[j];
            w0[j] = (short)f2bf(wf0);
            w1[j] = (short)f2bf(wf1);
            kc = fmaf(wf0, mf0[j], kc);
            kc = fmaf(wf1, mf1[j], kc);
        }
        kc += __shfl_xor(kc, 16);
        kc += __shfl_xor(kc, 32);          // K_c for class cm
        cstv[ct] = fmaf(-0.5f, kc, logpr[cm]);
        f32x4 a = {0.f, 0.f, 0.f, 0.f};
        a = __builtin_amdgcn_mfma_f32_16x16x32_bf16(a0, w0, a, 0, 0, 0);
        a = __builtin_amdgcn_mfma_f32_16x16x32_bf16(a1, w1, a, 0, 0, 0);
        acc[ct] = a;
    }

    // epilogue: D row = lg*4+r, col = lr
    float sbv[4];
    #pragma unroll
    for (int r = 0; r < 4; ++r) sbv[r] = __shfl(sbp, lg * 4 + r);
    #pragma unroll
    for (int ct = 0; ct < 4; ++ct) {
        int c = c0 + ct * 16 + lr;
        if (c < CC) {
            #pragma unroll
            for (int r = 0; r < 4; ++r) {
                int b = b0 + lg * 4 + r;
                out[(size_t)b * CC + c] = acc[ct][r] + cstv[ct] - 0.5f * sbv[r];
            }
        }
    }
}

extern "C" void kernel_launch(void* const* d_in, const int* in_sizes, int n_in,
                              void* d_out, int out_size, void* d_ws, size_t ws_size,
                              hipStream_t stream) {
    const float* z = (const float*)d_in[0];
    const int*   y = (const int*)d_in[1];
    float* out = (float*)d_out;

    // ws: all arrays written every call before read; no zeroing needed.
    float* mean     = (float*)d_ws;            // 64000 (class-major [c][d])
    float* logpr    = mean + DD * CC;          // 1000
    float* corrPart = logpr + CC;              // 125*64 = 8000
    float* T2part   = corrPart + NCB * DD;     // 16*64  = 1024

    k_stats<<<NCB + NTB, 256, 0, stream>>>(z, y, mean, logpr, corrPart, T2part);
    dim3 grid(BB / 64, (CC + 63) / 64);        // 32 x 16
    k_score_mfma<<<grid, 256, 0, stream>>>(z, mean, logpr, corrPart, T2part, out);
}